// Round 10
// baseline (348.823 us; speedup 1.0000x reference)
//
#include <hip/hip_runtime.h>
#include <hip/hip_cooperative_groups.h>
#include <cstdint>

namespace cg = cooperative_groups;

// Problem constants (B=1024, S=4096, P=512)
constexpr int B_ = 1024;
constexpr int S_ = 4096;
constexpr int P_ = 512;

// Fixed-point packing: count<<48 | sum*2^21 (native ds_add_u64; round-6 win)
constexpr float FPSCALE = 2097152.0f;          // 2^21
constexpr double INV_FPSCALE = 1.0 / 2097152.0;

// ---------------------------------------------------------------------------
// Fused cooperative kernel, 1024 blocks x 256 threads (4/CU).
// KEY FIX vs round 4: NO register state lives across grid.sync() -- phase 3
// re-reads its idx row (L3-hot, ~1-2us) instead of caching it in registers.
// Round 4 kept iv[16]+d[16] across both syncs -> compiler spilled to scratch
// (VGPR=28, VALUBusy 0.9%, 400us). Each phase is now self-contained.
// ---------------------------------------------------------------------------
__global__ __launch_bounds__(256, 4) void fused_kernel(
    const int* __restrict__ idx, const float* __restrict__ ds,
    const float* __restrict__ sum_in, const float* __restrict__ cnt_in,
    const float* __restrict__ dur_in, const float* __restrict__ rv,
    const float* __restrict__ dn_in, const int* __restrict__ padp,
    float* __restrict__ out, float* __restrict__ part,
    float* __restrict__ table, float* __restrict__ stats) {
  __shared__ unsigned long long acc[4][P_];   // 16 KB; reused every phase
  __shared__ int   red_a[4], red_b[4], red_c[4];
  __shared__ int   bcast[3];    // n, dmax, denom
  __shared__ float fbcast[2];   // dni, num

  const int t = threadIdx.x;
  const int b = blockIdx.x;
  const int w = t >> 6;

  // ---------------- phase 1: histogram of row b ----------------
  {
#pragma unroll
    for (int c = 0; c < 4; ++c) { acc[c][t] = 0ull; acc[c][t + 256] = 0ull; }
    __syncthreads();

    unsigned long long* __restrict__ ma = acc[w];
    const int* __restrict__ rowidx = idx + (size_t)b * S_;
    const float* __restrict__ rowds = ds + (size_t)b * S_;
#pragma unroll
    for (int k = 0; k < 4; ++k) {
      const int j0 = k * 1024 + t * 4;
      int4   i4 = *reinterpret_cast<const int4*>(rowidx + j0);
      float4 d4 = *reinterpret_cast<const float4*>(rowds + j0);
      atomicAdd(&ma[i4.x], (1ull << 48) | (unsigned long long)(d4.x * FPSCALE));
      atomicAdd(&ma[i4.y], (1ull << 48) | (unsigned long long)(d4.y * FPSCALE));
      atomicAdd(&ma[i4.z], (1ull << 48) | (unsigned long long)(d4.z * FPSCALE));
      atomicAdd(&ma[i4.w], (1ull << 48) | (unsigned long long)(d4.w * FPSCALE));
    }
    __syncthreads();

    const int b0 = 2 * t, b1 = 2 * t + 1;
    const unsigned long long v0 =
        acc[0][b0] + acc[1][b0] + acc[2][b0] + acc[3][b0];
    const unsigned long long v1 =
        acc[0][b1] + acc[1][b1] + acc[2][b1] + acc[3][b1];
    const unsigned long long MASK48 = (1ull << 48) - 1;
    float4 ov;
    ov.x = (float)((double)(v0 & MASK48) * INV_FPSCALE);
    ov.y = (float)(v0 >> 48);
    ov.z = (float)((double)(v1 & MASK48) * INV_FPSCALE);
    ov.w = (float)(v1 >> 48);
    *reinterpret_cast<float4*>(part + (size_t)b * 1024 + 4 * t) = ov;
  }

  __threadfence();
  cg::this_grid().sync();

  // ---------------- phase 2: blocks 0..511 reduce bin b ----------------
  if (b < P_) {
    float2* sred = reinterpret_cast<float2*>(acc);   // 2 KB of the 16 KB
    float sx = 0.f, sy = 0.f;
#pragma unroll
    for (int r = 0; r < 4; ++r) {
      const float2 v = *reinterpret_cast<const float2*>(
          part + (size_t)(t + r * 256) * 1024 + 2 * b);
      sx += v.x; sy += v.y;
    }
    sred[t] = make_float2(sx, sy);
    __syncthreads();
    if (t < 128) { sred[t].x += sred[t + 128].x; sred[t].y += sred[t + 128].y; }
    __syncthreads();
    if (t < 64) {
      float ss = sred[t].x + sred[t + 64].x;
      float cc = sred[t].y + sred[t + 64].y;
#pragma unroll
      for (int o = 32; o > 0; o >>= 1) {
        ss += __shfl_down(ss, o);
        cc += __shfl_down(cc, o);
      }
      if (t == 0) {
        const float sn = ss + sum_in[b];
        const float cn = cc + cnt_in[b];
        const float tv = (cc > 0.f) ? sn / fmaxf(cn, 1.f) : dur_in[b];
        table[b] = tv;
        out[(size_t)B_ * S_ + b] = tv;   // duration_new output
        if (b >= 2 && b < 7) {
          stats[b - 2]      = sn;
          stats[5 + b - 2]  = cn;
          stats[10 + b - 2] = cc;
        }
      }
    }
  }

  __threadfence();
  cg::this_grid().sync();

  // ---------------- phase 3: eval row b (idx re-read from L3) ----------------
  float* tbl = reinterpret_cast<float*>(acc);
  tbl[t]       = table[t];
  tbl[t + 256] = table[t + 256];
  const int pad = padp[0];

  if (t == 0) {
    float ss = 0.f, cc = 0.f, rc = 0.f;
#pragma unroll
    for (int i = 0; i < 5; ++i) {
      ss += stats[i]; cc += stats[5 + i]; rc += stats[10 + i];
    }
    const float dnn = (rc > 0.f) ? (ss / cc) : dn_in[0];
    const float dni = truncf(dnn);
    fbcast[0] = dni;
    fbcast[1] = dni - truncf(rv[0] * dnn);   // num = int(dn) - int(rv*dn)
    if (b == 0) out[(size_t)B_ * S_ + P_] = dnn;  // dn_new output
  }
  __syncthreads();

  const int* __restrict__ rowidx = idx + (size_t)b * S_;
  int d[16];
  int jfirst = 0x7fffffff;
  int dmax   = 0x80000000;
#pragma unroll
  for (int k = 0; k < 4; ++k) {
    const int j0 = k * 1024 + t * 4;
    int4 iv = *reinterpret_cast<const int4*>(rowidx + j0);
    const int ivm[4] = {iv.x, iv.y, iv.z, iv.w};
#pragma unroll
    for (int m = 0; m < 4; ++m) {
      const int j = j0 + m;
      const int dd = (int)tbl[ivm[m]];  // trunc toward zero, vals >= 0
      d[k * 4 + m] = dd;
      if (j >= 1) {
        if (ivm[m] == pad && j < jfirst) jfirst = j;
        if (dd > dmax) dmax = dd;
      }
    }
  }

  const int lane = t & 63;
  int a = jfirst, bb = dmax;
#pragma unroll
  for (int o = 32; o > 0; o >>= 1) {
    a  = min(a,  __shfl_down(a,  o));
    bb = max(bb, __shfl_down(bb, o));
  }
  if (lane == 0) { red_a[w] = a; red_b[w] = bb; }
  __syncthreads();
  if (t == 0) {
    int na = min(min(red_a[0], red_a[1]), min(red_a[2], red_a[3]));
    int nb = max(max(red_b[0], red_b[1]), max(red_b[2], red_b[3]));
    bcast[0] = (na == 0x7fffffff) ? 1 : na;   // n
    bcast[1] = nb;                            // row max dur (j>=1)
  }
  __syncthreads();
  const int n       = bcast[0];
  const int dmaxall = bcast[1];

  int dsum = 0;
#pragma unroll
  for (int k = 0; k < 4; ++k) {
    const int j0 = k * 1024 + t * 4;
#pragma unroll
    for (int m = 0; m < 4; ++m) {
      const int j = j0 + m;
      if (j >= 1 && j < n) dsum += d[k * 4 + m];
    }
  }
#pragma unroll
  for (int o = 32; o > 0; o >>= 1) dsum += __shfl_down(dsum, o);
  if (lane == 0) red_c[w] = dsum;
  __syncthreads();
  if (t == 0) bcast[2] = red_c[0] + red_c[1] + red_c[2] + red_c[3];
  __syncthreads();
  const int denom = bcast[2];

  const float dni = fbcast[0];
  const float num = fbcast[1];
  const float denomf = (float)denom;
  const float rc2 = (n == 1) ? 1.0f
                             : fminf(1.0f, num / (denomf > 0.f ? denomf : 1.0f));
  const int delta = max(dmaxall, 1);
  const int dur0  = max(1, (int)dni - delta);

  float* __restrict__ rowout = out + (size_t)b * S_;
#pragma unroll
  for (int k = 0; k < 4; ++k) {
    const int j0 = k * 1024 + t * 4;
    float4 ov;
    float* o = reinterpret_cast<float*>(&ov);
#pragma unroll
    for (int m = 0; m < 4; ++m) {
      const int j = j0 + m;
      const int dd = d[k * 4 + m];
      int v;
      if (j == 0)      v = dur0;
      else if (j < n)  v = max(1, (int)truncf(rc2 * (float)dd));
      else             v = dd;
      o[m] = (float)v;
    }
    *reinterpret_cast<float4*>(rowout + j0) = ov;
  }
}

// ---------------------------------------------------------------------------
extern "C" void kernel_launch(void* const* d_in, const int* in_sizes, int n_in,
                              void* d_out, int out_size, void* d_ws, size_t ws_size,
                              hipStream_t stream) {
  const int*   idx    = (const int*)d_in[0];
  const float* ds     = (const float*)d_in[1];
  const float* sum_in = (const float*)d_in[2];
  const float* cnt_in = (const float*)d_in[3];
  const float* dur_in = (const float*)d_in[4];
  const float* rv     = (const float*)d_in[5];
  const float* dn     = (const float*)d_in[6];
  const int*   pad    = (const int*)d_in[7];

  float* out   = (float*)d_out;
  float* part  = (float*)d_ws;                  // [1024][1024] = 4 MB
  float* table = part + (size_t)B_ * 1024;      // [512]
  float* stats = table + P_;                    // [15]

  void* args[] = {(void*)&idx, (void*)&ds, (void*)&sum_in, (void*)&cnt_in,
                  (void*)&dur_in, (void*)&rv, (void*)&dn, (void*)&pad,
                  (void*)&out, (void*)&part, (void*)&table, (void*)&stats};
  hipLaunchCooperativeKernel((void*)fused_kernel, dim3(B_), dim3(256),
                             args, 0, stream);
}

// Round 11
// 25.636 us; speedup vs baseline: 13.6069x; 13.6069x over previous
//
#include <hip/hip_runtime.h>
#include <cstdint>

// Problem constants (B=1024, S=4096, P=512)
constexpr int B_ = 1024;
constexpr int S_ = 4096;
constexpr int P_ = 512;
constexpr int NSCAT = 512;   // scatter blocks (partial-histogram rows)

// Fixed-point scale for packed LDS accumulation: sum in low 48 bits
// (ds * 2^21), count in high 16 bits. One native ds_add_u64 per element.
constexpr float FPSCALE = 2097152.0f;          // 2^21
constexpr double INV_FPSCALE = 1.0 / 2097152.0;

// ---------------------------------------------------------------------------
// SESSION NOTES (measured, MI355X/gfx950):
//  - f32/int LDS atomicAdd pairs lower to CAS loops -> packed u64 ds_add_u64
//    was the big win (43 -> 25.7 us, round 6).
//  - Device-scope atomics on few lines: ~50-100 cy/op serialized (rounds 1,8).
//  - grid.sync() costs ~170 us/sync at 1024 blocks (rounds 4,10) -> coop
//    fusion unviable; 3-dispatch chain is the optimum found.
//  - Dispatch/graph overhead ~15 us of the 25.4 us total; kernel work ~10 us,
//    within ~2x of pure traffic roofline (~55 MB @ 6.3 TB/s).
// ---------------------------------------------------------------------------

// ---------------------------------------------------------------------------
// Kernel A: per-block histogram of (sum ds, count) over P=512 bins.
// 512 blocks x 256 threads x 32 elements = B*S exactly.
// Per-WAVE packed u64 LDS sub-histograms (4 copies): one atomicAdd(u64)
// per element -> guaranteed-native ds_add_u64 (no fp CAS-loop risk).
// Output: part[block][1024] interleaved {sum[bin], cnt[bin]} float pairs,
// written non-atomically (coalesced float4).
// ---------------------------------------------------------------------------
__global__ __launch_bounds__(256) void scatter_kernel(
    const int* __restrict__ idx, const float* __restrict__ ds,
    float* __restrict__ part) {
  __shared__ unsigned long long acc[4][P_];   // 16 KB
  const int t = threadIdx.x;
  const int w = t >> 6;
#pragma unroll
  for (int c = 0; c < 4; ++c) {
    acc[c][t] = 0ull; acc[c][t + 256] = 0ull;
  }
  __syncthreads();

  unsigned long long* __restrict__ ma = acc[w];
  const size_t base = (size_t)blockIdx.x * 8192 + (size_t)t * 4;
#pragma unroll
  for (int k = 0; k < 8; k += 2) {
    const size_t off0 = base + (size_t)k * 1024;
    const size_t off1 = off0 + 1024;
    int4   i0 = *reinterpret_cast<const int4*>(idx + off0);
    int4   i1 = *reinterpret_cast<const int4*>(idx + off1);
    float4 d0 = *reinterpret_cast<const float4*>(ds + off0);
    float4 d1 = *reinterpret_cast<const float4*>(ds + off1);
    atomicAdd(&ma[i0.x], (1ull << 48) | (unsigned long long)(d0.x * FPSCALE));
    atomicAdd(&ma[i0.y], (1ull << 48) | (unsigned long long)(d0.y * FPSCALE));
    atomicAdd(&ma[i0.z], (1ull << 48) | (unsigned long long)(d0.z * FPSCALE));
    atomicAdd(&ma[i0.w], (1ull << 48) | (unsigned long long)(d0.w * FPSCALE));
    atomicAdd(&ma[i1.x], (1ull << 48) | (unsigned long long)(d1.x * FPSCALE));
    atomicAdd(&ma[i1.y], (1ull << 48) | (unsigned long long)(d1.y * FPSCALE));
    atomicAdd(&ma[i1.z], (1ull << 48) | (unsigned long long)(d1.z * FPSCALE));
    atomicAdd(&ma[i1.w], (1ull << 48) | (unsigned long long)(d1.w * FPSCALE));
  }
  __syncthreads();

  // thread t flushes bins 2t and 2t+1 as one float4 (coalesced, deterministic)
  const int b0 = 2 * t, b1 = 2 * t + 1;
  const unsigned long long v0 =
      acc[0][b0] + acc[1][b0] + acc[2][b0] + acc[3][b0];
  const unsigned long long v1 =
      acc[0][b1] + acc[1][b1] + acc[2][b1] + acc[3][b1];
  const unsigned long long MASK48 = (1ull << 48) - 1;
  float4 ov;
  ov.x = (float)((double)(v0 & MASK48) * INV_FPSCALE);
  ov.y = (float)(v0 >> 48);
  ov.z = (float)((double)(v1 & MASK48) * INV_FPSCALE);
  ov.w = (float)(v1 >> 48);
  *reinterpret_cast<float4*>(part + (size_t)blockIdx.x * 1024 + 4 * t) = ov;
}

// ---------------------------------------------------------------------------
// Kernel B: one block per BIN (512 blocks x 256 threads). Thread t loads
// float2 {sum,cnt} at rows t and t+256 of its bin's column pair (2
// independent 8B loads, L2/L3-served), then LDS + shfl tree reduction.
// Thread 0 finalizes table[p]; bins 2..6 dump {sn, cn, raw_cnt} to stats.
// ---------------------------------------------------------------------------
__global__ __launch_bounds__(256) void reduce_finalize_kernel(
    const float* __restrict__ part,
    const float* __restrict__ sum_in, const float* __restrict__ cnt_in,
    const float* __restrict__ dur_in,
    float* __restrict__ table, float* __restrict__ stats,
    float* __restrict__ out_tail /* d_out + B*S : 512 table values */) {
  __shared__ float2 sred[256];
  const int t = threadIdx.x;
  const int p = blockIdx.x;

  const float2 a = *reinterpret_cast<const float2*>(
      part + (size_t)t * 1024 + 2 * p);
  const float2 b = *reinterpret_cast<const float2*>(
      part + (size_t)(t + 256) * 1024 + 2 * p);
  sred[t] = make_float2(a.x + b.x, a.y + b.y);
  __syncthreads();

  if (t < 128) {
    sred[t].x += sred[t + 128].x;
    sred[t].y += sred[t + 128].y;
  }
  __syncthreads();

  if (t < 64) {
    float ss = sred[t].x + sred[t + 64].x;
    float cc = sred[t].y + sred[t + 64].y;
#pragma unroll
    for (int o = 32; o > 0; o >>= 1) {
      ss += __shfl_down(ss, o);
      cc += __shfl_down(cc, o);
    }
    if (t == 0) {
      const float sn = ss + sum_in[p];
      const float cn = cc + cnt_in[p];
      const float tv = (cc > 0.f) ? sn / fmaxf(cn, 1.f) : dur_in[p];
      table[p]    = tv;
      out_tail[p] = tv;
      if (p >= 2 && p < 7) {
        stats[p - 2]      = sn;   // sum_new
        stats[5 + p - 2]  = cn;   // cnt_new
        stats[10 + p - 2] = cc;   // raw scatter count (for has_26)
      }
    }
  }
}

// ---------------------------------------------------------------------------
// Kernel C: per-row gather + rescale. 1 block (256 thr) per row; 16 cols/thr.
// Thread 0 of each block computes the dn scalars from stats (cheap, uniform);
// block 0 also writes dn_new to the output tail.
// ---------------------------------------------------------------------------
__global__ __launch_bounds__(256) void eval_kernel(
    const int* __restrict__ idx, const float* __restrict__ table,
    const float* __restrict__ stats, const float* __restrict__ rv,
    const float* __restrict__ dn_in, const int* __restrict__ padp,
    float* __restrict__ out) {
  __shared__ float tbl[P_];
  __shared__ int   red_a[4], red_b[4], red_c[4];
  __shared__ int   bcast[3];   // n, dmax, denom
  __shared__ float fbcast[2];  // dni, num

  const int t   = threadIdx.x;
  const int row = blockIdx.x;
  tbl[t]       = table[t];
  tbl[t + 256] = table[t + 256];
  const int pad = padp[0];

  if (t == 0) {
    float ss = 0.f, cc = 0.f, rc = 0.f;
#pragma unroll
    for (int i = 0; i < 5; ++i) {
      ss += stats[i]; cc += stats[5 + i]; rc += stats[10 + i];
    }
    const float dnn = (rc > 0.f) ? (ss / cc) : dn_in[0];
    const float dni = truncf(dnn);
    fbcast[0] = dni;
    fbcast[1] = dni - truncf(rv[0] * dnn);   // num = int(dn) - int(rv*dn)
    if (row == 0) out[(size_t)B_ * S_ + P_] = dnn;  // dn_new output
  }
  __syncthreads();

  const int* __restrict__ rowidx = idx + (size_t)row * S_;
  int d[16];
  int jfirst = 0x7fffffff;
  int dmax   = 0x80000000;

#pragma unroll
  for (int k = 0; k < 4; ++k) {
    const int j0 = k * 1024 + t * 4;
    int4 iv = *reinterpret_cast<const int4*>(rowidx + j0);
    const int ivm[4] = {iv.x, iv.y, iv.z, iv.w};
#pragma unroll
    for (int m = 0; m < 4; ++m) {
      const int j = j0 + m;
      const int dd = (int)tbl[ivm[m]];  // trunc-toward-zero, values >= 0
      d[k * 4 + m] = dd;
      if (j >= 1) {
        if (ivm[m] == pad && j < jfirst) jfirst = j;
        if (dd > dmax) dmax = dd;
      }
    }
  }

  // phase-1 reduce: min(jfirst), max(dmax) over 256 threads
  const int wid = t >> 6, lane = t & 63;
  int a = jfirst, b = dmax;
#pragma unroll
  for (int o = 32; o > 0; o >>= 1) {
    a = min(a, __shfl_down(a, o));
    b = max(b, __shfl_down(b, o));
  }
  if (lane == 0) { red_a[wid] = a; red_b[wid] = b; }
  __syncthreads();
  if (t == 0) {
    int na = min(min(red_a[0], red_a[1]), min(red_a[2], red_a[3]));
    int nb = max(max(red_b[0], red_b[1]), max(red_b[2], red_b[3]));
    bcast[0] = (na == 0x7fffffff) ? 1 : na;   // n
    bcast[1] = nb;                            // row max dur (j>=1)
  }
  __syncthreads();
  const int n       = bcast[0];
  const int dmaxall = bcast[1];

  // phase-2 reduce: denom = sum of d[j] for 1 <= j < n
  int dsum = 0;
#pragma unroll
  for (int k = 0; k < 4; ++k) {
    const int j0 = k * 1024 + t * 4;
#pragma unroll
    for (int m = 0; m < 4; ++m) {
      const int j = j0 + m;
      if (j >= 1 && j < n) dsum += d[k * 4 + m];
    }
  }
#pragma unroll
  for (int o = 32; o > 0; o >>= 1) dsum += __shfl_down(dsum, o);
  if (lane == 0) red_c[wid] = dsum;
  __syncthreads();
  if (t == 0) bcast[2] = red_c[0] + red_c[1] + red_c[2] + red_c[3];
  __syncthreads();
  const int denom = bcast[2];

  const float dni = fbcast[0];
  const float num = fbcast[1];
  const float denomf = (float)denom;
  const float rc = (n == 1) ? 1.0f
                            : fminf(1.0f, num / (denomf > 0.f ? denomf : 1.0f));
  const int delta = max(dmaxall, 1);
  const int dur0  = max(1, (int)dni - delta);

  float* __restrict__ rowout = out + (size_t)row * S_;
#pragma unroll
  for (int k = 0; k < 4; ++k) {
    const int j0 = k * 1024 + t * 4;
    float4 ov;
    float* o = reinterpret_cast<float*>(&ov);
#pragma unroll
    for (int m = 0; m < 4; ++m) {
      const int j = j0 + m;
      const int dd = d[k * 4 + m];
      int v;
      if (j == 0)      v = dur0;
      else if (j < n)  v = max(1, (int)truncf(rc * (float)dd));
      else             v = dd;
      o[m] = (float)v;
    }
    *reinterpret_cast<float4*>(rowout + j0) = ov;
  }
}

// ---------------------------------------------------------------------------
extern "C" void kernel_launch(void* const* d_in, const int* in_sizes, int n_in,
                              void* d_out, int out_size, void* d_ws, size_t ws_size,
                              hipStream_t stream) {
  const int*   idx    = (const int*)d_in[0];
  const float* ds     = (const float*)d_in[1];
  const float* sum_in = (const float*)d_in[2];
  const float* cnt_in = (const float*)d_in[3];
  const float* dur_in = (const float*)d_in[4];
  const float* rv     = (const float*)d_in[5];
  const float* dn     = (const float*)d_in[6];
  const int*   pad    = (const int*)d_in[7];

  float* out = (float*)d_out;

  float* part  = (float*)d_ws;                 // [512][1024] = 2 MB
  float* table = part + (size_t)NSCAT * 1024;  // [512]
  float* stats = table + P_;                   // [15] : sn[5], cn[5], raw[5]

  scatter_kernel<<<NSCAT, 256, 0, stream>>>(idx, ds, part);
  reduce_finalize_kernel<<<P_, 256, 0, stream>>>(part, sum_in, cnt_in, dur_in,
                                                 table, stats,
                                                 out + (size_t)B_ * S_);
  eval_kernel<<<1024, 256, 0, stream>>>(idx, table, stats, rv, dn, pad, out);
}